// Round 2
// baseline (639.598 us; speedup 1.0000x reference)
//
#include <hip/hip_runtime.h>

constexpr int NN = 50000;
constexpr int NE = 1600000;
constexpr int NG = 1000;
constexpr int NBLK = 196;            // scan blocks: 196*256 = 50176 >= NN

// workspace layout in 4-byte units
constexpr int OFF_DEG   = 0;         // int[50176]   (zeroed)
constexpr int OFF_SUMS  = 50176;     // f32[64000]   (zeroed)
constexpr int OFF_CNT   = 114176;    // f32[1024]    (zeroed)
constexpr int ZERO_UNITS= 115200;
constexpr int OFF_OFFS  = 115200;    // int[50176]
constexpr int OFF_CURS  = 165376;    // int[50176]
constexpr int OFF_BTOT  = 215552;    // int[256]
constexpr int OFF_BEXCL = 215808;    // int[256]
constexpr int OFF_SE    = 216064;    // int2[NE] = 3200000 units (8B aligned: 216064 even)
constexpr int OFF_H1    = 3416064;   // f32[NN*64] = 3200000 units
// total = 6,616,064 units = 26.5 MB

// ---------- CSR build ----------
__global__ __launch_bounds__(256) void hist_kernel(const int* __restrict__ eidx,
                                                   int* __restrict__ deg) {
    int tid = blockIdx.x * blockDim.x + threadIdx.x;
    int stride = gridDim.x * blockDim.x;
    for (int e = tid; e < NE; e += stride) atomicAdd(&deg[eidx[NE + e]], 1);
}

__global__ __launch_bounds__(256) void scanA_kernel(const int* __restrict__ deg,
                                                    int* __restrict__ offs,
                                                    int* __restrict__ btot) {
    __shared__ int s[256];
    int t = threadIdx.x;
    int i = blockIdx.x * 256 + t;
    int v = (i < NN) ? deg[i] : 0;
    s[t] = v; __syncthreads();
    for (int o = 1; o < 256; o <<= 1) {
        int u = (t >= o) ? s[t - o] : 0;
        __syncthreads();
        s[t] += u;
        __syncthreads();
    }
    offs[i] = s[t] - v;                 // exclusive within block
    if (t == 255) btot[blockIdx.x] = s[255];
}

__global__ __launch_bounds__(256) void scanB_kernel(const int* __restrict__ btot,
                                                    int* __restrict__ bexcl) {
    __shared__ int s[256];
    int t = threadIdx.x;
    int v = (t < NBLK) ? btot[t] : 0;
    s[t] = v; __syncthreads();
    for (int o = 1; o < 256; o <<= 1) {
        int u = (t >= o) ? s[t - o] : 0;
        __syncthreads();
        s[t] += u;
        __syncthreads();
    }
    bexcl[t] = s[t] - v;
}

__global__ __launch_bounds__(256) void scanC_kernel(int* __restrict__ offs,
                                                    const int* __restrict__ bexcl,
                                                    int* __restrict__ cursor) {
    int i = blockIdx.x * 256 + threadIdx.x;
    int o = offs[i] + bexcl[blockIdx.x];
    offs[i] = o;
    cursor[i] = o;
}

__global__ __launch_bounds__(256) void scatter_kernel(const int* __restrict__ eidx,
                                                      int* __restrict__ cursor,
                                                      int2* __restrict__ se) {
    int tid = blockIdx.x * blockDim.x + threadIdx.x;
    int stride = gridDim.x * blockDim.x;
    for (int e = tid; e < NE; e += stride) {
        int src = eidx[e];
        int dst = eidx[NE + e];
        int pos = atomicAdd(&cursor[dst], 1);
        se[pos] = make_int2(src, e);
    }
}

// ---------- Layer 1 fused: aggregate (7-dim, 8 edges x 8 dims per wave) + MLP ----------
__global__ __launch_bounds__(256) void layer1_kernel(
    const float* __restrict__ x, const float* __restrict__ edge_attr,
    const int2* __restrict__ se, const int* __restrict__ offs,
    const float* __restrict__ We1, const float* __restrict__ be1,
    const float* __restrict__ W1a, const float* __restrict__ b1a,
    const float* __restrict__ W1b, const float* __restrict__ b1b,
    float* __restrict__ h1)
{
    __shared__ float sWe[32];          // [k=0..3][d=0..7], col 7 zeroed
    __shared__ float sbe[8];
    __shared__ float sWa[7 * 64];
    __shared__ float sWb[64 * 64];
    __shared__ float sba[64], sbb[64];
    __shared__ float tbuf[4][64];
    int tid = threadIdx.x;
    if (tid < 32) { int k = tid >> 3, dd = tid & 7; sWe[tid] = (dd < 7) ? We1[k * 7 + dd] : 0.f; }
    if (tid < 8)  sbe[tid] = (tid < 7) ? be1[tid] : 0.f;
    for (int i = tid; i < 7 * 64; i += 256) sWa[i] = W1a[i];
    for (int i = tid; i < 64 * 64; i += 256) sWb[i] = W1b[i];
    if (tid < 64) { sba[tid] = b1a[tid]; sbb[tid] = b1b[tid]; }
    __syncthreads();

    const int w = tid >> 6, lane = tid & 63;
    const int n = blockIdx.x * 4 + w;            // 12500 blocks * 4 = 50000 exactly
    const int off = offs[n];
    const int deg = offs[n + 1] - off;
    const int jg = lane >> 3, d = lane & 7;

    float acc = 0.f;
    for (int j0 = 0; j0 < deg; j0 += 8) {
        int j = j0 + jg;
        float v = 0.f;
        if (j < deg) {
            int2 s = se[off + j];
            const float4 ea = *(const float4*)(edge_attr + (size_t)s.y * 4);
            float xv = (d < 7) ? x[(size_t)s.x * 7 + d] : 0.f;
            float t = sbe[d] + ea.x * sWe[d] + ea.y * sWe[8 + d]
                    + ea.z * sWe[16 + d] + ea.w * sWe[24 + d] + xv;
            v = (d < 7) ? fmaxf(t, 0.f) : 0.f;
        }
        acc += v;
    }
    acc += __shfl_xor(acc, 8);
    acc += __shfl_xor(acc, 16);
    acc += __shfl_xor(acc, 32);        // now every lane with lane&7==d holds full aggr_d
    float zl = ((d < 7) ? x[(size_t)n * 7 + d] : 0.f) + acc;

    // MLP: lane = output dim
    float t = sba[lane];
    #pragma unroll
    for (int k = 0; k < 7; ++k) t += __shfl(zl, k) * sWa[k * 64 + lane];
    t = fmaxf(t, 0.f);
    tbuf[w][lane] = t;                 // wave64 lockstep, no barrier
    float o = sbb[lane];
    #pragma unroll 8
    for (int k = 0; k < 64; ++k) o += tbuf[w][k] * sWb[k * 64 + lane];
    h1[(size_t)n * 64 + lane] = fmaxf(o, 0.f);
}

// ---------- Layer 2 fused: aggregate (lane=dim) + MLP + pool ----------
__global__ __launch_bounds__(256) void layer2_kernel(
    const float* __restrict__ h1, const float* __restrict__ edge_attr,
    const int2* __restrict__ se, const int* __restrict__ offs,
    const float* __restrict__ We2, const float* __restrict__ be2,
    const float* __restrict__ W2a, const float* __restrict__ b2a,
    const float* __restrict__ W2b, const float* __restrict__ b2b,
    const int* __restrict__ batch,
    float* __restrict__ sums, float* __restrict__ cnt)
{
    __shared__ float sWe[256];
    __shared__ float sbe[64];
    __shared__ float sWa[64 * 64];
    __shared__ float sWb[64 * 64];
    __shared__ float sba[64], sbb[64];
    __shared__ float zbuf[4][64];
    __shared__ float tbuf[4][64];
    int tid = threadIdx.x;
    if (tid < 256) sWe[tid] = We2[tid];
    for (int i = tid; i < 64 * 64; i += 256) { sWa[i] = W2a[i]; sWb[i] = W2b[i]; }
    if (tid < 64) { sbe[tid] = be2[tid]; sba[tid] = b2a[tid]; sbb[tid] = b2b[tid]; }
    __syncthreads();

    const int w = tid >> 6, lane = tid & 63;
    const int n = blockIdx.x * 4 + w;
    const int off = offs[n];
    const int deg = offs[n + 1] - off;

    float acc = 0.f;
    int j = 0;
    for (; j + 2 <= deg; j += 2) {
        int2 s0 = se[off + j];
        int2 s1 = se[off + j + 1];
        const float4 e0 = *(const float4*)(edge_attr + (size_t)s0.y * 4);
        const float4 e1 = *(const float4*)(edge_attr + (size_t)s1.y * 4);
        float g0 = h1[(size_t)s0.x * 64 + lane];
        float g1 = h1[(size_t)s1.x * 64 + lane];
        float b0 = sbe[lane] + e0.x * sWe[lane] + e0.y * sWe[64 + lane]
                 + e0.z * sWe[128 + lane] + e0.w * sWe[192 + lane];
        float b1 = sbe[lane] + e1.x * sWe[lane] + e1.y * sWe[64 + lane]
                 + e1.z * sWe[128 + lane] + e1.w * sWe[192 + lane];
        acc += fmaxf(g0 + b0, 0.f) + fmaxf(g1 + b1, 0.f);
    }
    if (j < deg) {
        int2 s0 = se[off + j];
        const float4 e0 = *(const float4*)(edge_attr + (size_t)s0.y * 4);
        float g0 = h1[(size_t)s0.x * 64 + lane];
        float b0 = sbe[lane] + e0.x * sWe[lane] + e0.y * sWe[64 + lane]
                 + e0.z * sWe[128 + lane] + e0.w * sWe[192 + lane];
        acc += fmaxf(g0 + b0, 0.f);
    }

    float z = h1[(size_t)n * 64 + lane] + acc;
    zbuf[w][lane] = z;
    float t = sba[lane];
    #pragma unroll 8
    for (int k = 0; k < 64; ++k) t += zbuf[w][k] * sWa[k * 64 + lane];
    t = fmaxf(t, 0.f);
    tbuf[w][lane] = t;
    float o = sbb[lane];
    #pragma unroll 8
    for (int k = 0; k < 64; ++k) o += tbuf[w][k] * sWb[k * 64 + lane];
    o = fmaxf(o, 0.f);
    int g = batch[n];
    atomicAdd(sums + (size_t)g * 64 + lane, o);
    if (lane == 0) atomicAdd(cnt + g, 1.0f);
}

// ---------- FC ----------
__global__ __launch_bounds__(256) void fc_kernel(
    const float* __restrict__ sums, const float* __restrict__ cnt,
    const float* __restrict__ Wfc, const float* __restrict__ bfc,
    float* __restrict__ out)
{
    int gid = blockIdx.x * blockDim.x + threadIdx.x;
    if (gid >= NG * 12) return;
    int g = gid / 12, jj = gid - g * 12;
    float inv = 1.f / fmaxf(cnt[g], 1.f);
    float acc = bfc[jj];
    #pragma unroll 8
    for (int k = 0; k < 64; ++k) acc += sums[(size_t)g * 64 + k] * inv * Wfc[k * 12 + jj];
    out[gid] = acc;
}

extern "C" void kernel_launch(void* const* d_in, const int* in_sizes, int n_in,
                              void* d_out, int out_size, void* d_ws, size_t ws_size,
                              hipStream_t stream)
{
    (void)in_sizes; (void)n_in; (void)out_size; (void)ws_size;
    const float* x    = (const float*)d_in[0];
    const float* ea   = (const float*)d_in[1];
    const int*   eidx = (const int*)d_in[2];
    const int*   batch= (const int*)d_in[3];
    const float* We1  = (const float*)d_in[4];
    const float* be1  = (const float*)d_in[5];
    const float* W1a  = (const float*)d_in[6];
    const float* b1a  = (const float*)d_in[7];
    const float* W1b  = (const float*)d_in[8];
    const float* b1b  = (const float*)d_in[9];
    const float* We2  = (const float*)d_in[10];
    const float* be2  = (const float*)d_in[11];
    const float* W2a  = (const float*)d_in[12];
    const float* b2a  = (const float*)d_in[13];
    const float* W2b  = (const float*)d_in[14];
    const float* b2b  = (const float*)d_in[15];
    const float* Wfc  = (const float*)d_in[16];
    const float* bfc  = (const float*)d_in[17];
    float* out = (float*)d_out;
    float* ws  = (float*)d_ws;

    int*   deg    = (int*)(ws + OFF_DEG);
    float* sums   = ws + OFF_SUMS;
    float* cnt    = ws + OFF_CNT;
    int*   offs   = (int*)(ws + OFF_OFFS);
    int*   cursor = (int*)(ws + OFF_CURS);
    int*   btot   = (int*)(ws + OFF_BTOT);
    int*   bexcl  = (int*)(ws + OFF_BEXCL);
    int2*  se     = (int2*)(ws + OFF_SE);
    float* h1     = ws + OFF_H1;

    hipMemsetAsync(d_ws, 0, (size_t)ZERO_UNITS * 4, stream);

    hist_kernel   <<<1024, 256, 0, stream>>>(eidx, deg);
    scanA_kernel  <<<NBLK, 256, 0, stream>>>(deg, offs, btot);
    scanB_kernel  <<<1,    256, 0, stream>>>(btot, bexcl);
    scanC_kernel  <<<NBLK, 256, 0, stream>>>(offs, bexcl, cursor);
    scatter_kernel<<<2048, 256, 0, stream>>>(eidx, cursor, se);
    layer1_kernel <<<12500, 256, 0, stream>>>(x, ea, se, offs, We1, be1, W1a, b1a, W1b, b1b, h1);
    layer2_kernel <<<12500, 256, 0, stream>>>(h1, ea, se, offs, We2, be2, W2a, b2a, W2b, b2b,
                                              batch, sums, cnt);
    fc_kernel     <<<(NG * 12 + 255) / 256, 256, 0, stream>>>(sums, cnt, Wfc, bfc, out);
}

// Round 3
// 525.479 us; speedup vs baseline: 1.2172x; 1.2172x over previous
//
#include <hip/hip_runtime.h>

constexpr int NN = 50000;
constexpr int NE = 1600000;
constexpr int NG = 1000;
constexpr int NBLK = 196;            // scan blocks: 196*256 = 50176 >= NN

// workspace layout in 4-byte units
constexpr int OFF_DEG   = 0;          // int[50176]  (zeroed)
constexpr int OFF_SUMS  = 50176;      // f32[64000]  (zeroed)
constexpr int OFF_CNT   = 114176;     // f32[1024]   (zeroed)
constexpr int ZERO_UNITS= 115200;
constexpr int OFF_OFFS  = 115200;     // int[50176]
constexpr int OFF_CURS  = 165376;     // int[50176]
constexpr int OFF_BTOT  = 215552;     // int[256]
constexpr int OFF_BEXCL = 215808;     // int[256]
constexpr int OFF_SRCP  = 216064;     // int[NE]
constexpr int OFF_EAP   = 1816064;    // float4[NE] (16B aligned: /4 ok)
constexpr int OFF_Z     = 8216064;    // f32[NN*64]
constexpr int OFF_H1    = 11416064;   // f32[NN*64]
// total = 14,616,064 units = 58.5 MB

// ---------- CSR build ----------
__global__ __launch_bounds__(256) void hist_kernel(const int* __restrict__ eidx,
                                                   int* __restrict__ deg) {
    int tid = blockIdx.x * blockDim.x + threadIdx.x;
    int stride = gridDim.x * blockDim.x;
    for (int e = tid; e < NE; e += stride) atomicAdd(&deg[eidx[NE + e]], 1);
}

__global__ __launch_bounds__(256) void scanA_kernel(const int* __restrict__ deg,
                                                    int* __restrict__ offs,
                                                    int* __restrict__ btot) {
    __shared__ int s[256];
    int t = threadIdx.x;
    int i = blockIdx.x * 256 + t;
    int v = (i < NN) ? deg[i] : 0;
    s[t] = v; __syncthreads();
    for (int o = 1; o < 256; o <<= 1) {
        int u = (t >= o) ? s[t - o] : 0;
        __syncthreads();
        s[t] += u;
        __syncthreads();
    }
    offs[i] = s[t] - v;
    if (t == 255) btot[blockIdx.x] = s[255];
}

__global__ __launch_bounds__(256) void scanB_kernel(const int* __restrict__ btot,
                                                    int* __restrict__ bexcl) {
    __shared__ int s[256];
    int t = threadIdx.x;
    int v = (t < NBLK) ? btot[t] : 0;
    s[t] = v; __syncthreads();
    for (int o = 1; o < 256; o <<= 1) {
        int u = (t >= o) ? s[t - o] : 0;
        __syncthreads();
        s[t] += u;
        __syncthreads();
    }
    bexcl[t] = s[t] - v;
}

__global__ __launch_bounds__(256) void scanC_kernel(int* __restrict__ offs,
                                                    const int* __restrict__ bexcl,
                                                    int* __restrict__ cursor) {
    int i = blockIdx.x * 256 + threadIdx.x;
    int o = offs[i] + bexcl[blockIdx.x];
    offs[i] = o;
    cursor[i] = o;
}

// scatter edges into CSR order; also permute edge_attr so both layers read it coalesced
__global__ __launch_bounds__(256) void scatter_kernel(const int* __restrict__ eidx,
                                                      const float* __restrict__ edge_attr,
                                                      int* __restrict__ cursor,
                                                      int* __restrict__ srcp,
                                                      float4* __restrict__ eap) {
    int tid = blockIdx.x * blockDim.x + threadIdx.x;
    int stride = gridDim.x * blockDim.x;
    for (int e = tid; e < NE; e += stride) {
        int src = eidx[e];
        int dst = eidx[NE + e];
        float4 ea = *(const float4*)(edge_attr + (size_t)e * 4);
        int pos = atomicAdd(&cursor[dst], 1);
        srcp[pos] = src;
        eap[pos] = ea;
    }
}

// ---------- Layer 1 fused: aggregate (8 edges x 8 dims per wave) + MLP ----------
__global__ __launch_bounds__(256) void layer1_kernel(
    const float* __restrict__ x, const int* __restrict__ srcp,
    const float4* __restrict__ eap, const int* __restrict__ offs,
    const float* __restrict__ We1, const float* __restrict__ be1,
    const float* __restrict__ W1a, const float* __restrict__ b1a,
    const float* __restrict__ W1b, const float* __restrict__ b1b,
    float* __restrict__ h1)
{
    __shared__ float sWe[32];          // [k=0..3][d=0..7], col 7 zeroed
    __shared__ float sbe[8];
    __shared__ float sWa[7 * 64];
    __shared__ float sWb[64 * 64];
    __shared__ float sba[64], sbb[64];
    __shared__ float tbuf[4][64];
    int tid = threadIdx.x;
    if (tid < 32) { int k = tid >> 3, dd = tid & 7; sWe[tid] = (dd < 7) ? We1[k * 7 + dd] : 0.f; }
    if (tid < 8)  sbe[tid] = (tid < 7) ? be1[tid] : 0.f;
    for (int i = tid; i < 7 * 64; i += 256) sWa[i] = W1a[i];
    for (int i = tid; i < 64 * 64; i += 256) sWb[i] = W1b[i];
    if (tid < 64) { sba[tid] = b1a[tid]; sbb[tid] = b1b[tid]; }
    __syncthreads();

    const int w = tid >> 6, lane = tid & 63;
    const int n = blockIdx.x * 4 + w;            // 12500 * 4 = 50000
    const int off = offs[n];
    const int deg = offs[n + 1] - off;
    const int jg = lane >> 3, d = lane & 7;

    float acc = 0.f;
    for (int j0 = 0; j0 < deg; j0 += 8) {
        int j = j0 + jg;
        float v = 0.f;
        if (j < deg) {
            int s = srcp[off + j];
            const float4 ea = eap[off + j];          // coalesced 128B per wave-batch
            float xv = (d < 7) ? x[(size_t)s * 7 + d] : 0.f;
            float t = sbe[d] + ea.x * sWe[d] + ea.y * sWe[8 + d]
                    + ea.z * sWe[16 + d] + ea.w * sWe[24 + d] + xv;
            v = (d < 7) ? fmaxf(t, 0.f) : 0.f;
        }
        acc += v;
    }
    acc += __shfl_xor(acc, 8);
    acc += __shfl_xor(acc, 16);
    acc += __shfl_xor(acc, 32);
    float zl = ((d < 7) ? x[(size_t)n * 7 + d] : 0.f) + acc;

    float t = sba[lane];
    #pragma unroll
    for (int k = 0; k < 7; ++k) t += __shfl(zl, k) * sWa[k * 64 + lane];
    t = fmaxf(t, 0.f);
    tbuf[w][lane] = t;                 // wave64 lockstep, no barrier
    float o = sbb[lane];
    #pragma unroll 8
    for (int k = 0; k < 64; ++k) o += tbuf[w][k] * sWb[k * 64 + lane];
    h1[(size_t)n * 64 + lane] = fmaxf(o, 0.f);
}

// ---------- Layer 2 aggregation (high occupancy, 8 gathers in flight) ----------
__global__ __launch_bounds__(256) void aggr2_kernel(
    const float* __restrict__ h1, const int* __restrict__ srcp,
    const float4* __restrict__ eap, const int* __restrict__ offs,
    const float* __restrict__ We2, const float* __restrict__ be2,
    float* __restrict__ z)
{
    __shared__ float sWe[256];
    __shared__ float sbe[64];
    int tid = threadIdx.x;
    sWe[tid] = We2[tid];
    if (tid < 64) sbe[tid] = be2[tid];
    __syncthreads();

    const int w = tid >> 6, lane = tid & 63;
    const int lane8 = lane & 7;
    const int n = blockIdx.x * 4 + w;
    const int off = offs[n];
    const int deg = offs[n + 1] - off;

    const float w0 = sWe[lane], w1 = sWe[64 + lane], w2 = sWe[128 + lane], w3 = sWe[192 + lane];
    const float bb = sbe[lane];

    float selfh = h1[(size_t)n * 64 + lane];
    float acc = 0.f;
    for (int jb = 0; jb < deg; jb += 8) {
        int m = deg - jb;
        int kmax = (m < 8) ? m : 8;                  // wave-uniform
        int jj = off + jb + ((lane8 < m) ? lane8 : 0);
        int sv = srcp[jj];                           // lanes 0..7 hold the 8 srcs
        float4 ev = eap[jj];                         // lanes 0..7 hold the 8 edge_attrs
        int srcs[8];
        #pragma unroll
        for (int k = 0; k < 8; ++k) srcs[k] = __shfl(sv, k);
        float g[8];
        #pragma unroll
        for (int k = 0; k < 8; ++k)                  // 8 independent 256B gathers in flight
            g[k] = (k < kmax) ? h1[(size_t)srcs[k] * 64 + lane] : 0.f;
        #pragma unroll
        for (int k = 0; k < 8; ++k) {
            if (k < kmax) {
                float ex = __shfl(ev.x, k), ey = __shfl(ev.y, k);
                float ez = __shfl(ev.z, k), ew = __shfl(ev.w, k);
                float b = bb + ex * w0 + ey * w1 + ez * w2 + ew * w3;
                acc += fmaxf(g[k] + b, 0.f);
            }
        }
    }
    z[(size_t)n * 64 + lane] = selfh + acc;
}

// ---------- Layer 2 MLP + fused global-mean-pool ----------
__global__ __launch_bounds__(256) void mlp2_kernel(
    const float* __restrict__ z,
    const float* __restrict__ W2a, const float* __restrict__ b2a,
    const float* __restrict__ W2b, const float* __restrict__ b2b,
    const int* __restrict__ batch,
    float* __restrict__ sums, float* __restrict__ cnt)
{
    __shared__ float sWa[64 * 64];
    __shared__ float sWb[64 * 64];
    __shared__ float sba[64], sbb[64];
    __shared__ float zbuf[4][64];
    __shared__ float tbuf[4][64];
    int tid = threadIdx.x;
    for (int i = tid; i < 64 * 64; i += 256) { sWa[i] = W2a[i]; sWb[i] = W2b[i]; }
    if (tid < 64) { sba[tid] = b2a[tid]; sbb[tid] = b2b[tid]; }
    __syncthreads();

    const int w = tid >> 6, lane = tid & 63;
    const int n = blockIdx.x * 4 + w;
    float zd = z[(size_t)n * 64 + lane];
    zbuf[w][lane] = zd;
    float t = sba[lane];
    #pragma unroll 8
    for (int k = 0; k < 64; ++k) t += zbuf[w][k] * sWa[k * 64 + lane];
    t = fmaxf(t, 0.f);
    tbuf[w][lane] = t;
    float o = sbb[lane];
    #pragma unroll 8
    for (int k = 0; k < 64; ++k) o += tbuf[w][k] * sWb[k * 64 + lane];
    o = fmaxf(o, 0.f);
    int g = batch[n];
    atomicAdd(sums + (size_t)g * 64 + lane, o);
    if (lane == 0) atomicAdd(cnt + g, 1.0f);
}

// ---------- FC ----------
__global__ __launch_bounds__(256) void fc_kernel(
    const float* __restrict__ sums, const float* __restrict__ cnt,
    const float* __restrict__ Wfc, const float* __restrict__ bfc,
    float* __restrict__ out)
{
    int gid = blockIdx.x * blockDim.x + threadIdx.x;
    if (gid >= NG * 12) return;
    int g = gid / 12, jj = gid - g * 12;
    float inv = 1.f / fmaxf(cnt[g], 1.f);
    float acc = bfc[jj];
    #pragma unroll 8
    for (int k = 0; k < 64; ++k) acc += sums[(size_t)g * 64 + k] * inv * Wfc[k * 12 + jj];
    out[gid] = acc;
}

extern "C" void kernel_launch(void* const* d_in, const int* in_sizes, int n_in,
                              void* d_out, int out_size, void* d_ws, size_t ws_size,
                              hipStream_t stream)
{
    (void)in_sizes; (void)n_in; (void)out_size; (void)ws_size;
    const float* x    = (const float*)d_in[0];
    const float* ea   = (const float*)d_in[1];
    const int*   eidx = (const int*)d_in[2];
    const int*   batch= (const int*)d_in[3];
    const float* We1  = (const float*)d_in[4];
    const float* be1  = (const float*)d_in[5];
    const float* W1a  = (const float*)d_in[6];
    const float* b1a  = (const float*)d_in[7];
    const float* W1b  = (const float*)d_in[8];
    const float* b1b  = (const float*)d_in[9];
    const float* We2  = (const float*)d_in[10];
    const float* be2  = (const float*)d_in[11];
    const float* W2a  = (const float*)d_in[12];
    const float* b2a  = (const float*)d_in[13];
    const float* W2b  = (const float*)d_in[14];
    const float* b2b  = (const float*)d_in[15];
    const float* Wfc  = (const float*)d_in[16];
    const float* bfc  = (const float*)d_in[17];
    float* out = (float*)d_out;
    float* ws  = (float*)d_ws;

    int*    deg    = (int*)(ws + OFF_DEG);
    float*  sums   = ws + OFF_SUMS;
    float*  cnt    = ws + OFF_CNT;
    int*    offs   = (int*)(ws + OFF_OFFS);
    int*    cursor = (int*)(ws + OFF_CURS);
    int*    btot   = (int*)(ws + OFF_BTOT);
    int*    bexcl  = (int*)(ws + OFF_BEXCL);
    int*    srcp   = (int*)(ws + OFF_SRCP);
    float4* eap    = (float4*)(ws + OFF_EAP);
    float*  z      = ws + OFF_Z;
    float*  h1     = ws + OFF_H1;

    hipMemsetAsync(d_ws, 0, (size_t)ZERO_UNITS * 4, stream);

    hist_kernel   <<<1024, 256, 0, stream>>>(eidx, deg);
    scanA_kernel  <<<NBLK, 256, 0, stream>>>(deg, offs, btot);
    scanB_kernel  <<<1,    256, 0, stream>>>(btot, bexcl);
    scanC_kernel  <<<NBLK, 256, 0, stream>>>(offs, bexcl, cursor);
    scatter_kernel<<<2048, 256, 0, stream>>>(eidx, ea, cursor, srcp, eap);
    layer1_kernel <<<12500, 256, 0, stream>>>(x, srcp, eap, offs, We1, be1, W1a, b1a, W1b, b1b, h1);
    aggr2_kernel  <<<12500, 256, 0, stream>>>(h1, srcp, eap, offs, We2, be2, z);
    mlp2_kernel   <<<12500, 256, 0, stream>>>(z, W2a, b2a, W2b, b2b, batch, sums, cnt);
    fc_kernel     <<<(NG * 12 + 255) / 256, 256, 0, stream>>>(sums, cnt, Wfc, bfc, out);
}